// Round 1
// baseline (3471.989 us; speedup 1.0000x reference)
//
#include <hip/hip_runtime.h>

#define NN 100000
#define NE 1200000
#define NG 2048

// ---------------- degree / norm ----------------
__global__ void k_deg(const int* __restrict__ col, float* __restrict__ deg, int E) {
    int e = blockIdx.x * blockDim.x + threadIdx.x;
    if (e < E) atomicAdd(&deg[col[e]], 1.0f);
}

__global__ void k_norm(const int* __restrict__ row, const int* __restrict__ col,
                       const float* __restrict__ deg, float* __restrict__ norm, int E) {
    int e = blockIdx.x * blockDim.x + threadIdx.x;
    if (e < E) {
        float dr = deg[row[e]], dc = deg[col[e]];
        float ir = dr > 0.f ? 1.0f / sqrtf(dr) : 0.f;
        float ic = dc > 0.f ? 1.0f / sqrtf(dc) : 0.f;
        norm[e] = ir * ic;
    }
}

// ---------------- small node-GEMM ----------------
// out[n, k*O+o] = (bias? bias[k*O+o]:0) + (add? add[n*K*O+k*O+o]:0)
//              + sum_f in[n*inStride + k*inKStride + f] * W[k,f,o]
template <int F, int K, int O>
__global__ void k_mm(const float* __restrict__ X, int inStride, int inKStride,
                     const float* __restrict__ W,
                     const float* __restrict__ bias, const float* __restrict__ add,
                     float* __restrict__ out, int relu, int N) {
    __shared__ float Ws[K * F * O];
    for (int i = threadIdx.x; i < K * F * O; i += blockDim.x) Ws[i] = W[i];
    __syncthreads();
    const int KO = K * O;
    int idx = blockIdx.x * blockDim.x + threadIdx.x;
    if (idx >= N * KO) return;
    int n = idx / KO;
    int rem = idx - n * KO;
    int k = rem / O;
    int o = rem - k * O;
    const float* xp = X + (long long)n * inStride + k * inKStride;
    const float* wp = Ws + (k * F) * O + o;
    float acc = bias ? bias[rem] : 0.f;
    if (add) acc += add[idx];
#pragma unroll
    for (int f = 0; f < F; ++f) acc = fmaf(xp[f], wp[f * O], acc);
    if (relu) acc = fmaxf(acc, 0.f);
    out[idx] = acc;
}

// ---------------- edge propagate (gather * norm -> scatter-add) ----------------
template <int FC>
__global__ void k_prop(const float* __restrict__ src, float* __restrict__ dst,
                       const int* __restrict__ row, const int* __restrict__ col,
                       const float* __restrict__ norm, int E) {
    int idx = blockIdx.x * blockDim.x + threadIdx.x;
    if (idx >= E * FC) return;
    int e = idx / FC;
    int f = idx - e * FC;
    int r = row[e], c = col[e];
    float v = src[(long long)r * FC + f] * norm[e];
    atomicAdd(&dst[(long long)c * FC + f], v);
}

// ---------------- mean over K stacks ----------------
template <int K, int O>
__global__ void k_mean(const float* __restrict__ in, float* __restrict__ out,
                       int relu, int N) {
    int idx = blockIdx.x * blockDim.x + threadIdx.x;
    if (idx >= N * O) return;
    int n = idx / O;
    int o = idx - n * O;
    float s = 0.f;
#pragma unroll
    for (int k = 0; k < K; ++k) s += in[(long long)n * K * O + k * O + o];
    s *= (1.0f / K);
    if (relu) s = fmaxf(s, 0.f);
    out[idx] = s;
}

// ---------------- output init + fused pool & head ----------------
__global__ void k_initout(float* __restrict__ out, const float* __restrict__ bg, int G) {
    int g = blockIdx.x * blockDim.x + threadIdx.x;
    if (g < G) out[g] = bg[0];
}

__global__ void k_pool(const float* __restrict__ h2, const int* __restrict__ batch,
                       const float* __restrict__ wg, float* __restrict__ out, int N) {
    int idx = blockIdx.x * blockDim.x + threadIdx.x;
    if (idx >= N * 64) return;
    int n = idx >> 6;
    int f = idx & 63;
    float v = h2[(long long)n * 64 + f] * wg[f];
#pragma unroll
    for (int off = 32; off > 0; off >>= 1) v += __shfl_down(v, off, 64);
    if (f == 0) atomicAdd(&out[batch[n]], v);
}

static inline int cdiv(long long a, int b) { return (int)((a + b - 1) / b); }

extern "C" void kernel_launch(void* const* d_in, const int* in_sizes, int n_in,
                              void* d_out, int out_size, void* d_ws, size_t ws_size,
                              hipStream_t stream) {
    const float* x   = (const float*)d_in[0];
    const int*   ei  = (const int*)d_in[1];
    const int*   row = ei;
    const int*   col = ei + NE;
    const int*   batch = (const int*)d_in[2];
    const float* w1i = (const float*)d_in[3];
    const float* w1w = (const float*)d_in[4];
    const float* w1r = (const float*)d_in[5];
    const float* w1b = (const float*)d_in[6];
    const float* w2i = (const float*)d_in[7];
    const float* w2w = (const float*)d_in[8];
    const float* w2r = (const float*)d_in[9];
    const float* w2b = (const float*)d_in[10];
    const float* wg  = (const float*)d_in[11];
    const float* bg  = (const float*)d_in[12];
    float* out = (float*)d_out;

    float* A    = (float*)d_ws;                 // [N,192]
    float* B    = A + (size_t)NN * 192;         // [N,192]
    float* norm = B + (size_t)NN * 192;         // [E]
    float* h1   = norm + NE;                    // [N,16] (deg aliases here first)
    float* deg  = h1;

    const int T = 256;

    // ---- gcn_norm ----
    hipMemsetAsync(deg, 0, (size_t)NN * 4, stream);
    k_deg<<<cdiv(NE, T), T, 0, stream>>>(col, deg, NE);
    k_norm<<<cdiv(NE, T), T, 0, stream>>>(row, col, deg, norm, NE);

    // ---- ARMA layer 1: 75 -> 16, K=3, T=2, relu ----
    // t=0: A = x @ w1_init  [N,48]
    k_mm<75, 3, 16><<<cdiv((long long)NN * 48, T), T, 0, stream>>>(
        x, 75, 0, w1i, nullptr, nullptr, A, 0, NN);
    hipMemsetAsync(B, 0, (size_t)NN * 48 * 4, stream);
    k_prop<48><<<cdiv((long long)NE * 48, T), T, 0, stream>>>(A, B, row, col, norm, NE);
    // A = x @ w1_root + B + bias, relu
    k_mm<75, 3, 16><<<cdiv((long long)NN * 48, T), T, 0, stream>>>(
        x, 75, 0, w1r, w1b, B, A, 1, NN);
    // t=1: B = A @ w1_w (per-stack)
    k_mm<16, 3, 16><<<cdiv((long long)NN * 48, T), T, 0, stream>>>(
        A, 48, 16, w1w, nullptr, nullptr, B, 0, NN);
    hipMemsetAsync(A, 0, (size_t)NN * 48 * 4, stream);
    k_prop<48><<<cdiv((long long)NE * 48, T), T, 0, stream>>>(B, A, row, col, norm, NE);
    k_mm<75, 3, 16><<<cdiv((long long)NN * 48, T), T, 0, stream>>>(
        x, 75, 0, w1r, w1b, A, B, 1, NN);
    // h1 = mean_k(B), relu (no-op, values >= 0)
    k_mean<3, 16><<<cdiv((long long)NN * 16, T), T, 0, stream>>>(B, h1, 1, NN);

    // ---- ARMA layer 2: 16 -> 64, K=3, T=2, no act ----
    k_mm<16, 3, 64><<<cdiv((long long)NN * 192, T), T, 0, stream>>>(
        h1, 16, 0, w2i, nullptr, nullptr, A, 0, NN);
    hipMemsetAsync(B, 0, (size_t)NN * 192 * 4, stream);
    k_prop<192><<<cdiv((long long)NE * 192, T), T, 0, stream>>>(A, B, row, col, norm, NE);
    k_mm<16, 3, 64><<<cdiv((long long)NN * 192, T), T, 0, stream>>>(
        h1, 16, 0, w2r, w2b, B, A, 0, NN);
    k_mm<64, 3, 64><<<cdiv((long long)NN * 192, T), T, 0, stream>>>(
        A, 192, 64, w2w, nullptr, nullptr, B, 0, NN);
    hipMemsetAsync(A, 0, (size_t)NN * 192 * 4, stream);
    k_prop<192><<<cdiv((long long)NE * 192, T), T, 0, stream>>>(B, A, row, col, norm, NE);
    k_mm<16, 3, 64><<<cdiv((long long)NN * 192, T), T, 0, stream>>>(
        h1, 16, 0, w2r, w2b, A, B, 0, NN);
    // h2 = mean_k(B) -> reuse A as h2 [N,64]
    k_mean<3, 64><<<cdiv((long long)NN * 64, T), T, 0, stream>>>(B, A, 0, NN);

    // ---- global_add_pool + linear head ----
    k_initout<<<cdiv(NG, T), T, 0, stream>>>(out, bg, NG);
    k_pool<<<cdiv((long long)NN * 64, T), T, 0, stream>>>(A, batch, wg, out, NN);
}

// Round 2
// 1418.285 us; speedup vs baseline: 2.4480x; 2.4480x over previous
//
#include <hip/hip_runtime.h>

#define NN 100000
#define NE 1200000
#define NG 2048

static inline int cdiv(long long a, int b) { return (int)((a + b - 1) / b); }

// ---------------- CSR build: histogram / dinv / scan / scatter ----------------
__global__ void k_hist(const int* __restrict__ col, int* __restrict__ cnt, int E) {
    int e = blockIdx.x * blockDim.x + threadIdx.x;
    if (e < E) atomicAdd(&cnt[col[e]], 1);
}

__global__ void k_dinv(const int* __restrict__ cnt, float* __restrict__ dinv, int N) {
    int n = blockIdx.x * blockDim.x + threadIdx.x;
    if (n < N) {
        int c = cnt[n];
        dinv[n] = c > 0 ? rsqrtf((float)c) : 0.f;
    }
}

// per-block exclusive scan of cnt -> excl, block totals -> btot
__global__ void k_scan1(const int* __restrict__ cnt, int* __restrict__ excl,
                        int* __restrict__ btot, int N) {
    __shared__ int s[256];
    int tid = threadIdx.x;
    int i = blockIdx.x * 256 + tid;
    int v = (i < N) ? cnt[i] : 0;
    s[tid] = v;
    __syncthreads();
    for (int off = 1; off < 256; off <<= 1) {
        int t = (tid >= off) ? s[tid - off] : 0;
        __syncthreads();
        s[tid] += t;
        __syncthreads();
    }
    if (i < N) excl[i] = s[tid] - v;
    if (tid == 255) btot[blockIdx.x] = s[255];
}

// single-block scan of block totals (NB <= 512)
__global__ void k_scan2(const int* __restrict__ btot, int* __restrict__ boff, int NB) {
    __shared__ int s[512];
    int tid = threadIdx.x;
    int v = (tid < NB) ? btot[tid] : 0;
    s[tid] = v;
    __syncthreads();
    for (int off = 1; off < 512; off <<= 1) {
        int t = (tid >= off) ? s[tid - off] : 0;
        __syncthreads();
        s[tid] += t;
        __syncthreads();
    }
    if (tid < NB) boff[tid] = s[tid] - v;
}

__global__ void k_scan3(const int* __restrict__ excl, const int* __restrict__ boff,
                        int* __restrict__ rowptr, int* __restrict__ cursor, int N) {
    int i = blockIdx.x * blockDim.x + threadIdx.x;
    if (i < N) {
        int rp = excl[i] + boff[i >> 8];
        rowptr[i] = rp;
        cursor[i] = rp;
    }
    if (i == 0) rowptr[N] = NE;
}

__global__ void k_scatter(const int* __restrict__ row, const int* __restrict__ col,
                          int* __restrict__ cursor, int* __restrict__ esrc, int E) {
    int e = blockIdx.x * blockDim.x + threadIdx.x;
    if (e < E) {
        int c = col[e];
        int p = atomicAdd(&cursor[c], 1);
        esrc[p] = row[e];
    }
}

// ---------------- node-GEMM, grid-stride, W in LDS once/block ----------------
// out[n, k*O+o] = dinv[n] * sum_f X[n*xs + k*xks + f] * W[k,f,o]
template <int F, int K, int O>
__global__ void k_mm(const float* __restrict__ X, int xs, int xks,
                     const float* __restrict__ W, const float* __restrict__ dinv,
                     float* __restrict__ out, int N) {
    __shared__ float Ws[K * F * O];
    for (int i = threadIdx.x; i < K * F * O; i += blockDim.x) Ws[i] = W[i];
    __syncthreads();
    const int KO = K * O;
    const int total = N * KO;
    const int stride = gridDim.x * blockDim.x;
    for (int idx = blockIdx.x * blockDim.x + threadIdx.x; idx < total; idx += stride) {
        int n = idx / KO;
        int rem = idx - n * KO;
        int k = rem / O;
        int o = rem - k * O;
        const float* xp = X + (size_t)n * xs + k * xks;
        const float* wp = Ws + k * F * O + o;
        float acc = 0.f;
#pragma unroll
        for (int f = 0; f < F; ++f) acc = fmaf(xp[f], wp[f * O], acc);
        out[idx] = acc * dinv[n];
    }
}

// ---------------- fused CSR-gather prop + root + bias (+relu) ----------------
// out[n,f] = act( dinv[n] * sum_{in-edges} src[r,f]  +  x0[n,:]@wr[k,:,o] + bias[f] )
// (src already pre-scaled by dinv[r] at producer)
template <int FR, int K, int O, int RELU>
__global__ void k_prop(const float* __restrict__ src,
                       const float* __restrict__ x0, int x0s,
                       const float* __restrict__ wr, const float* __restrict__ bias,
                       const int* __restrict__ rowptr, const int* __restrict__ esrc,
                       const float* __restrict__ dinv,
                       float* __restrict__ out, int N) {
    __shared__ float Ws[K * FR * O];
    for (int i = threadIdx.x; i < K * FR * O; i += blockDim.x) Ws[i] = wr[i];
    __syncthreads();
    const int FC = K * O;
    const int total = N * FC;
    const int stride = gridDim.x * blockDim.x;
    for (int idx = blockIdx.x * blockDim.x + threadIdx.x; idx < total; idx += stride) {
        int n = idx / FC;
        int f = idx - n * FC;
        int k = f / O;
        int o = f - k * O;
        int beg = rowptr[n], end = rowptr[n + 1];
        float acc = 0.f;
        for (int p = beg; p < end; ++p) {
            int r = esrc[p];
            acc += src[(size_t)r * FC + f];
        }
        acc *= dinv[n];
        // root term
        float rt = bias[f];
        const float* xp = x0 + (size_t)n * x0s;
        const float* wp = Ws + k * FR * O + o;
#pragma unroll
        for (int ff = 0; ff < FR; ++ff) rt = fmaf(xp[ff], wp[ff * O], rt);
        acc += rt;
        if (RELU) acc = fmaxf(acc, 0.f);
        out[idx] = acc;
    }
}

// ---------------- mean over K stacks ----------------
template <int K, int O>
__global__ void k_mean(const float* __restrict__ in, float* __restrict__ out,
                       int relu, int N) {
    int idx = blockIdx.x * blockDim.x + threadIdx.x;
    if (idx >= N * O) return;
    int n = idx / O;
    int o = idx - n * O;
    float s = 0.f;
#pragma unroll
    for (int k = 0; k < K; ++k) s += in[(size_t)n * K * O + k * O + o];
    s *= (1.0f / K);
    if (relu) s = fmaxf(s, 0.f);
    out[idx] = s;
}

// ---------------- output init + fused mean/pool/head ----------------
__global__ void k_initout(float* __restrict__ out, const float* __restrict__ bg, int G) {
    int g = blockIdx.x * blockDim.x + threadIdx.x;
    if (g < G) out[g] = bg[0];
}

// h2 = mean_k(B[n, k*64+f]); v = h2*wg[f]; wave-reduce 64; atomicAdd out[batch[n]]
__global__ void k_pool(const float* __restrict__ B, const int* __restrict__ batch,
                       const float* __restrict__ wg, float* __restrict__ out, int N) {
    int idx = blockIdx.x * blockDim.x + threadIdx.x;
    if (idx >= N * 64) return;
    int n = idx >> 6;
    int f = idx & 63;
    const float* bp = B + (size_t)n * 192;
    float s = (bp[f] + bp[64 + f] + bp[128 + f]) * (1.0f / 3.0f);
    float v = s * wg[f];
#pragma unroll
    for (int off = 32; off > 0; off >>= 1) v += __shfl_down(v, off, 64);
    if (f == 0) atomicAdd(&out[batch[n]], v);
}

extern "C" void kernel_launch(void* const* d_in, const int* in_sizes, int n_in,
                              void* d_out, int out_size, void* d_ws, size_t ws_size,
                              hipStream_t stream) {
    const float* x   = (const float*)d_in[0];
    const int*   ei  = (const int*)d_in[1];
    const int*   row = ei;
    const int*   col = ei + NE;
    const int*   batch = (const int*)d_in[2];
    const float* w1i = (const float*)d_in[3];
    const float* w1w = (const float*)d_in[4];
    const float* w1r = (const float*)d_in[5];
    const float* w1b = (const float*)d_in[6];
    const float* w2i = (const float*)d_in[7];
    const float* w2w = (const float*)d_in[8];
    const float* w2r = (const float*)d_in[9];
    const float* w2b = (const float*)d_in[10];
    const float* wg  = (const float*)d_in[11];
    const float* bg  = (const float*)d_in[12];
    float* out = (float*)d_out;

    // workspace layout (all 4B elems)
    float* A    = (float*)d_ws;                  // [N,192]
    float* B    = A + (size_t)NN * 192;          // [N,192]
    float* h1   = B + (size_t)NN * 192;          // [N,16]
    float* dinv = h1 + (size_t)NN * 16;          // [N]
    int*   cnt  = (int*)(dinv + NN);             // [N]
    int*   excl = cnt + NN;                      // [N]
    int*   rowptr = excl + NN;                   // [N+1]
    int*   cursor = rowptr + NN + 1;             // [N]
    int*   btot = cursor + NN;                   // [512]
    int*   boff = btot + 512;                    // [512]
    int*   esrc = boff + 512;                    // [E]

    const int T = 256;
    const int NB1 = cdiv(NN, 256);               // 391

    // ---- CSR build + dinv ----
    hipMemsetAsync(cnt, 0, (size_t)NN * 4, stream);
    k_hist<<<cdiv(NE, T), T, 0, stream>>>(col, cnt, NE);
    k_dinv<<<cdiv(NN, T), T, 0, stream>>>(cnt, dinv, NN);
    k_scan1<<<NB1, 256, 0, stream>>>(cnt, excl, btot, NN);
    k_scan2<<<1, 512, 0, stream>>>(btot, boff, NB1);
    k_scan3<<<cdiv(NN, T), T, 0, stream>>>(excl, boff, rowptr, cursor, NN);
    k_scatter<<<cdiv(NE, T), T, 0, stream>>>(row, col, cursor, esrc, NE);

    // ---- ARMA layer 1: 75 -> 16, K=3, T=2, relu ----
    k_mm<75, 3, 16><<<2048, T, 0, stream>>>(x, 75, 0, w1i, dinv, A, NN);
    k_prop<75, 3, 16, 1><<<4096, T, 0, stream>>>(A, x, 75, w1r, w1b,
                                                 rowptr, esrc, dinv, B, NN);
    k_mm<16, 3, 16><<<2048, T, 0, stream>>>(B, 48, 16, w1w, dinv, A, NN);
    k_prop<75, 3, 16, 1><<<4096, T, 0, stream>>>(A, x, 75, w1r, w1b,
                                                 rowptr, esrc, dinv, B, NN);
    k_mean<3, 16><<<cdiv((long long)NN * 16, T), T, 0, stream>>>(B, h1, 1, NN);

    // ---- ARMA layer 2: 16 -> 64, K=3, T=2, no act ----
    k_mm<16, 3, 64><<<2048, T, 0, stream>>>(h1, 16, 0, w2i, dinv, A, NN);
    k_prop<16, 3, 64, 0><<<4096, T, 0, stream>>>(A, h1, 16, w2r, w2b,
                                                 rowptr, esrc, dinv, B, NN);
    k_mm<64, 3, 64><<<2048, T, 0, stream>>>(B, 192, 64, w2w, dinv, A, NN);
    k_prop<16, 3, 64, 0><<<4096, T, 0, stream>>>(A, h1, 16, w2r, w2b,
                                                 rowptr, esrc, dinv, B, NN);

    // ---- global_add_pool + linear head (fused with mean over K) ----
    k_initout<<<cdiv(NG, T), T, 0, stream>>>(out, bg, NG);
    k_pool<<<cdiv((long long)NN * 64, T), T, 0, stream>>>(B, batch, wg, out, NN);
}

// Round 3
// 695.833 us; speedup vs baseline: 4.9897x; 2.0383x over previous
//
#include <hip/hip_runtime.h>

#define NN 100000
#define NE 1200000
#define NG 2048

static inline int cdiv(long long a, int b) { return (int)((a + b - 1) / b); }

// ---------------- CSR build: histogram / dinv / scan / scatter ----------------
__global__ void k_hist(const int* __restrict__ col, int* __restrict__ cnt, int E) {
    int e = blockIdx.x * blockDim.x + threadIdx.x;
    if (e < E) atomicAdd(&cnt[col[e]], 1);
}

__global__ void k_dinv(const int* __restrict__ cnt, float* __restrict__ dinv, int N) {
    int n = blockIdx.x * blockDim.x + threadIdx.x;
    if (n < N) {
        int c = cnt[n];
        dinv[n] = c > 0 ? rsqrtf((float)c) : 0.f;
    }
}

__global__ void k_scan1(const int* __restrict__ cnt, int* __restrict__ excl,
                        int* __restrict__ btot, int N) {
    __shared__ int s[256];
    int tid = threadIdx.x;
    int i = blockIdx.x * 256 + tid;
    int v = (i < N) ? cnt[i] : 0;
    s[tid] = v;
    __syncthreads();
    for (int off = 1; off < 256; off <<= 1) {
        int t = (tid >= off) ? s[tid - off] : 0;
        __syncthreads();
        s[tid] += t;
        __syncthreads();
    }
    if (i < N) excl[i] = s[tid] - v;
    if (tid == 255) btot[blockIdx.x] = s[255];
}

__global__ void k_scan2(const int* __restrict__ btot, int* __restrict__ boff, int NB) {
    __shared__ int s[512];
    int tid = threadIdx.x;
    int v = (tid < NB) ? btot[tid] : 0;
    s[tid] = v;
    __syncthreads();
    for (int off = 1; off < 512; off <<= 1) {
        int t = (tid >= off) ? s[tid - off] : 0;
        __syncthreads();
        s[tid] += t;
        __syncthreads();
    }
    if (tid < NB) boff[tid] = s[tid] - v;
}

__global__ void k_scan3(const int* __restrict__ excl, const int* __restrict__ boff,
                        int* __restrict__ rowptr, int* __restrict__ cursor, int N) {
    int i = blockIdx.x * blockDim.x + threadIdx.x;
    if (i < N) {
        int rp = excl[i] + boff[i >> 8];
        rowptr[i] = rp;
        cursor[i] = rp;
    }
    if (i == 0) rowptr[N] = NE;
}

__global__ void k_scatter(const int* __restrict__ row, const int* __restrict__ col,
                          int* __restrict__ cursor, int* __restrict__ esrc, int E) {
    int e = blockIdx.x * blockDim.x + threadIdx.x;
    if (e < E) {
        int c = col[e];
        int p = atomicAdd(&cursor[c], 1);
        esrc[p] = row[e];
    }
}

// ---------------- node-GEMM, float4 outputs, W in LDS ----------------
// out[n, k*O + o..o+3] = dinv[n] * sum_f X[n*xs + k*xks + f] * W[k,f,o..o+3]
template <int F, int K, int O>
__global__ void k_mm(const float* __restrict__ X, int xs, int xks,
                     const float* __restrict__ W, const float* __restrict__ dinv,
                     float4* __restrict__ out4, int N) {
    constexpr int O4 = O / 4;
    constexpr int FC4 = K * O4;
    __shared__ float4 Ws[K * F * O4];
    const float4* W4 = (const float4*)W;
    for (int i = threadIdx.x; i < K * F * O4; i += blockDim.x) Ws[i] = W4[i];
    __syncthreads();
    const int total = N * FC4;
    const int stride = gridDim.x * blockDim.x;
    for (int idx = blockIdx.x * blockDim.x + threadIdx.x; idx < total; idx += stride) {
        int n = idx / FC4;
        int q = idx - n * FC4;       // float4 slot in row
        int k = q / O4;
        int o4 = q - k * O4;
        const float* xp = X + (size_t)n * xs + k * xks;
        const float4* wp = Ws + k * F * O4 + o4;
        float ax = 0.f, ay = 0.f, az = 0.f, aw = 0.f;
#pragma unroll
        for (int f = 0; f < F; ++f) {
            float xv = xp[f];
            float4 w = wp[f * O4];
            ax = fmaf(xv, w.x, ax);
            ay = fmaf(xv, w.y, ay);
            az = fmaf(xv, w.z, az);
            aw = fmaf(xv, w.w, aw);
        }
        float dn = dinv[n];
        float4 r;
        r.x = ax * dn; r.y = ay * dn; r.z = az * dn; r.w = aw * dn;
        out4[idx] = r;
    }
}

// ---------------- fused CSR-gather prop + root + bias (+relu), float4 ----------------
// out[n,f..f+3] = act( dinv[n]*sum_in src[r,f..f+3] + x0[n,:]@wr[k,:,o..o+3] + bias )
template <int FR, int K, int O, int RELU>
__global__ void k_prop(const float4* __restrict__ src4,
                       const float* __restrict__ x0, int x0s,
                       const float* __restrict__ wr, const float* __restrict__ bias,
                       const int* __restrict__ rowptr, const int* __restrict__ esrc,
                       const float* __restrict__ dinv,
                       float4* __restrict__ out4, int N) {
    constexpr int O4 = O / 4;
    constexpr int FC4 = K * O4;
    __shared__ float4 Ws[K * FR * O4];
    const float4* W4 = (const float4*)wr;
    for (int i = threadIdx.x; i < K * FR * O4; i += blockDim.x) Ws[i] = W4[i];
    __syncthreads();
    const float4* bias4 = (const float4*)bias;
    const int total = N * FC4;
    const int stride = gridDim.x * blockDim.x;
    for (int idx = blockIdx.x * blockDim.x + threadIdx.x; idx < total; idx += stride) {
        int n = idx / FC4;
        int q = idx - n * FC4;
        int k = q / O4;
        int o4 = q - k * O4;
        int beg = rowptr[n], end = rowptr[n + 1];
        float ax = 0.f, ay = 0.f, az = 0.f, aw = 0.f;
        int p = beg;
        for (; p + 3 < end; p += 4) {
            int r0 = esrc[p], r1 = esrc[p + 1], r2 = esrc[p + 2], r3 = esrc[p + 3];
            float4 v0 = src4[(size_t)r0 * FC4 + q];
            float4 v1 = src4[(size_t)r1 * FC4 + q];
            float4 v2 = src4[(size_t)r2 * FC4 + q];
            float4 v3 = src4[(size_t)r3 * FC4 + q];
            ax += (v0.x + v1.x) + (v2.x + v3.x);
            ay += (v0.y + v1.y) + (v2.y + v3.y);
            az += (v0.z + v1.z) + (v2.z + v3.z);
            aw += (v0.w + v1.w) + (v2.w + v3.w);
        }
        for (; p < end; ++p) {
            int r = esrc[p];
            float4 v = src4[(size_t)r * FC4 + q];
            ax += v.x; ay += v.y; az += v.z; aw += v.w;
        }
        float dn = dinv[n];
        // root term + bias
        float4 b = bias4[q];
        float rx = b.x, ry = b.y, rz = b.z, rw = b.w;
        const float* xp = x0 + (size_t)n * x0s;
        const float4* wp = Ws + k * FR * O4 + o4;
#pragma unroll
        for (int ff = 0; ff < FR; ++ff) {
            float xv = xp[ff];
            float4 w = wp[ff * O4];
            rx = fmaf(xv, w.x, rx);
            ry = fmaf(xv, w.y, ry);
            rz = fmaf(xv, w.z, rz);
            rw = fmaf(xv, w.w, rw);
        }
        float4 r;
        r.x = ax * dn + rx;
        r.y = ay * dn + ry;
        r.z = az * dn + rz;
        r.w = aw * dn + rw;
        if (RELU) {
            r.x = fmaxf(r.x, 0.f); r.y = fmaxf(r.y, 0.f);
            r.z = fmaxf(r.z, 0.f); r.w = fmaxf(r.w, 0.f);
        }
        out4[idx] = r;
    }
}

// ---------------- mean over K stacks (layer-1 -> h1) ----------------
template <int K, int O>
__global__ void k_mean(const float* __restrict__ in, float* __restrict__ out,
                       int relu, int N) {
    int idx = blockIdx.x * blockDim.x + threadIdx.x;
    if (idx >= N * O) return;
    int n = idx / O;
    int o = idx - n * O;
    float s = 0.f;
#pragma unroll
    for (int k = 0; k < K; ++k) s += in[(size_t)n * K * O + k * O + o];
    s *= (1.0f / K);
    if (relu) s = fmaxf(s, 0.f);
    out[idx] = s;
}

// ---------------- output init + fused mean/pool/head ----------------
__global__ void k_initout(float* __restrict__ out, const float* __restrict__ bg, int G) {
    int g = blockIdx.x * blockDim.x + threadIdx.x;
    if (g < G) out[g] = bg[0];
}

// thread per (n, o4): o4 in [0,16); mean over K=3 stacks, dot wg, 16-lane reduce
__global__ void k_pool(const float4* __restrict__ B4, const int* __restrict__ batch,
                       const float* __restrict__ wg, float* __restrict__ out, int N) {
    int idx = blockIdx.x * blockDim.x + threadIdx.x;
    if (idx >= N * 16) return;
    int n = idx >> 4;
    int o4 = idx & 15;
    const float4* bp = B4 + (size_t)n * 48 + o4;
    float4 v0 = bp[0], v1 = bp[16], v2 = bp[32];
    const float4 w = ((const float4*)wg)[o4];
    float v = (v0.x + v1.x + v2.x) * w.x + (v0.y + v1.y + v2.y) * w.y +
              (v0.z + v1.z + v2.z) * w.z + (v0.w + v1.w + v2.w) * w.w;
    v *= (1.0f / 3.0f);
#pragma unroll
    for (int off = 8; off > 0; off >>= 1) v += __shfl_down(v, off, 16);
    if (o4 == 0) atomicAdd(&out[batch[n]], v);
}

extern "C" void kernel_launch(void* const* d_in, const int* in_sizes, int n_in,
                              void* d_out, int out_size, void* d_ws, size_t ws_size,
                              hipStream_t stream) {
    const float* x   = (const float*)d_in[0];
    const int*   ei  = (const int*)d_in[1];
    const int*   row = ei;
    const int*   col = ei + NE;
    const int*   batch = (const int*)d_in[2];
    const float* w1i = (const float*)d_in[3];
    const float* w1w = (const float*)d_in[4];
    const float* w1r = (const float*)d_in[5];
    const float* w1b = (const float*)d_in[6];
    const float* w2i = (const float*)d_in[7];
    const float* w2w = (const float*)d_in[8];
    const float* w2r = (const float*)d_in[9];
    const float* w2b = (const float*)d_in[10];
    const float* wg  = (const float*)d_in[11];
    const float* bg  = (const float*)d_in[12];
    float* out = (float*)d_out;

    float* A    = (float*)d_ws;                  // [N,192]
    float* B    = A + (size_t)NN * 192;          // [N,192]
    float* h1   = B + (size_t)NN * 192;          // [N,16]
    float* dinv = h1 + (size_t)NN * 16;          // [N]
    int*   cnt  = (int*)(dinv + NN);             // [N]
    int*   excl = cnt + NN;                      // [N]
    int*   rowptr = excl + NN;                   // [N+1]
    int*   cursor = rowptr + NN + 1;             // [N]
    int*   btot = cursor + NN;                   // [512]
    int*   boff = btot + 512;                    // [512]
    int*   esrc = boff + 512;                    // [E]

    const int T = 256;
    const int NB1 = cdiv(NN, 256);

    // ---- CSR build + dinv ----
    hipMemsetAsync(cnt, 0, (size_t)NN * 4, stream);
    k_hist<<<cdiv(NE, T), T, 0, stream>>>(col, cnt, NE);
    k_dinv<<<cdiv(NN, T), T, 0, stream>>>(cnt, dinv, NN);
    k_scan1<<<NB1, 256, 0, stream>>>(cnt, excl, btot, NN);
    k_scan2<<<1, 512, 0, stream>>>(btot, boff, NB1);
    k_scan3<<<cdiv(NN, T), T, 0, stream>>>(excl, boff, rowptr, cursor, NN);
    k_scatter<<<cdiv(NE, T), T, 0, stream>>>(row, col, cursor, esrc, NE);

    // ---- ARMA layer 1: 75 -> 16, K=3, T=2, relu ----
    k_mm<75, 3, 16><<<2048, T, 0, stream>>>(x, 75, 0, w1i, dinv, (float4*)A, NN);
    k_prop<75, 3, 16, 1><<<2048, T, 0, stream>>>((const float4*)A, x, 75, w1r, w1b,
                                                 rowptr, esrc, dinv, (float4*)B, NN);
    k_mm<16, 3, 16><<<2048, T, 0, stream>>>(B, 48, 16, w1w, dinv, (float4*)A, NN);
    k_prop<75, 3, 16, 1><<<2048, T, 0, stream>>>((const float4*)A, x, 75, w1r, w1b,
                                                 rowptr, esrc, dinv, (float4*)B, NN);
    k_mean<3, 16><<<cdiv((long long)NN * 16, T), T, 0, stream>>>(B, h1, 1, NN);

    // ---- ARMA layer 2: 16 -> 64, K=3, T=2, no act ----
    k_mm<16, 3, 64><<<2048, T, 0, stream>>>(h1, 16, 0, w2i, dinv, (float4*)A, NN);
    k_prop<16, 3, 64, 0><<<2048, T, 0, stream>>>((const float4*)A, h1, 16, w2r, w2b,
                                                 rowptr, esrc, dinv, (float4*)B, NN);
    k_mm<64, 3, 64><<<2048, T, 0, stream>>>(B, 192, 64, w2w, dinv, (float4*)A, NN);
    k_prop<16, 3, 64, 0><<<2048, T, 0, stream>>>((const float4*)A, h1, 16, w2r, w2b,
                                                 rowptr, esrc, dinv, (float4*)B, NN);

    // ---- global_add_pool + linear head (fused with mean over K) ----
    k_initout<<<cdiv(NG, T), T, 0, stream>>>(out, bg, NG);
    k_pool<<<cdiv((long long)NN * 16, T), T, 0, stream>>>((const float4*)B, batch, wg, out, NN);
}